// Round 9
// baseline (223.146 us; speedup 1.0000x reference)
//
#include <hip/hip_runtime.h>
#include <hip/hip_bf16.h>
#include <math.h>

// Problem constants
#define BQ 4
#define NQ 100
#define MQ 50
#define HWSZ 65536
#define NP 112    // padded N rows in partials (7 x 16)
#define MP 64     // padded M (4 x 16)
#define NCH 128   // K chunks
#define KC 512    // HWSZ / NCH
#define BK 64     // K floats per step (r9: doubled; 8 sync events, not 16)
#define NSTEPS 8  // KC / BK
#define DEPTH 3   // LDS ring depth
#define ABYTES 28672  // A slab: 112 rows x 256 B
#define BBYTES 14336  // B slab:  56 rows x 256 B
#define SLAB (ABYTES + BBYTES)     // 43008 B; x3 = 129024 B dynamic LDS
#define DCLAMP 13.8155106f   // logit(1-1e-6) = -logit(1e-6)
#define ONESBF2 0x3F803F80u  // two bf16 1.0s

typedef __attribute__((ext_vector_type(8))) short short8;
typedef __attribute__((ext_vector_type(4))) float f32x4;
typedef __attribute__((address_space(3))) char as3char;
typedef const __attribute__((address_space(1))) char as1char;

// d = log(pm)-log(1-pm) = clamp(x, +-13.8155) EXACTLY (logit o clip o sigmoid).
// pm = sigmoid(clamp(x)); l1m = log(1-pm) = -log(1+e^xc).
__device__ __forceinline__ void xform2(float x, float& d, float& pm, float& l1m) {
    float xc = fminf(fmaxf(x, -DCLAMP), DCLAMP);
    d = xc;
    float e = __expf(xc);                       // in [1e-6, 1e6], no overflow
    float r = __builtin_amdgcn_rcpf(1.0f + e);
    pm = e * r;
    l1m = -__logf(1.0f + e);
}

// pack two floats -> two bf16 (RTNE) in one u32
__device__ __forceinline__ unsigned pk2(float a, float b) {
    __hip_bfloat162 h = __float22bfloat162_rn(float2{a, b});
    unsigned u;
    __builtin_memcpy(&u, &h, 4);
    return u;
}

// build a bf16x8 MFMA fragment from two float4
__device__ __forceinline__ short8 mk8(float4 a, float4 b) {
    union { short8 s; unsigned u[4]; } r;
    r.u[0] = pk2(a.x, a.y); r.u[1] = pk2(a.z, a.w);
    r.u[2] = pk2(b.x, b.y); r.u[3] = pk2(b.z, b.w);
    return r.s;
}

// build a bf16x8 MFMA fragment from 8 scalars
__device__ __forceinline__ short8 mk8s(float a0, float a1, float a2, float a3,
                                       float a4, float a5, float a6, float a7) {
    union { short8 s; unsigned u[4]; } r;
    r.u[0] = pk2(a0, a1); r.u[1] = pk2(a2, a3);
    r.u[2] = pk2(a4, a5); r.u[3] = pk2(a6, a7);
    return r.s;
}

// B-shared main kernel, BK=64 variant. Round-9 experiment: rounds 0-8 pinned
// at 80-93us across occupancy 11-36%, HBM 0-472MB, and 5 structural families;
// no pipe saturates (VALU-busy-time invariant ~27us; MFMA 3us; LDS ~8us;
// per-step wall time ~12000cy vs ~800cy critical path). Remaining suspect:
// the 16 per-step sync events (vmcnt drain + barrier), each gated by the
// slowest load in the block (tail latency x step count). This version halves
// the events: BK 32->64, 8 steps, one vmcnt+barrier each, same bytes, same
// math, same both-sides XOR swizzle (XOR hits bits 4-6; +128 k-slice offset
// commutes). Cost: 126KB LDS ring -> 1 block/CU.
__global__ __launch_bounds__(448)
void matcher_main(const float* __restrict__ pred_masks,  // [4][100][65536]
                  const float* __restrict__ tgt_masks,   // [4][50][65536]
                  float* __restrict__ part1,             // [4][128][112][64]
                  float* __restrict__ part2,             // [4][128][112][64]
                  float* __restrict__ rspart)            // [4][128][112]
{
    extern __shared__ __align__(16) char lds[];        // DEPTH * SLAB = 129024 B
    const int t    = threadIdx.x;
    const int lane = t & 63;
    const int wv   = t >> 6;          // wave = n-tile 0..6
    const int r16  = lane & 15;
    const int kg   = lane >> 4;       // k-group 0..3 (8 floats per k-slice)
    const int chunk = blockIdx.x;
    const int b     = blockIdx.y;
    const int n0    = wv * 16;
    const bool c50     = (r16 == 2);               // B col 50 ones-col (Sp)
    const bool onesrow = (wv == 6) && (r16 >= 4);  // A rows 100-111 ones (St)

    // ---- staging sources: 6 global_load_lds per thread per step ----
    // LDS[row*256 + (col ^ ((row&7)<<4))] = G[row][col] (col in 0..255 bytes).
    // global_load_lds writes linearly (uniform base + lane*16) so the SOURCE
    // carries the (involutive) swizzle; dest bases are wave-uniform.
    const float* gsA[4];
    #pragma unroll
    for (int j = 0; j < 4; ++j) {     // A: rows wv*16 .. wv*16+15
        const int o   = (wv * 4 + j) * 1024 + lane * 16;
        const int row = o >> 8;
        const int c   = (o ^ ((row & 7) << 4)) & 255;
        gsA[j] = pred_masks + (((long)(b * NQ + min(row, NQ - 1))) << 16)
               + chunk * KC + (c >> 2);
    }
    const float* gsB[2];
    #pragma unroll
    for (int j = 0; j < 2; ++j) {     // B: rows wv*8 .. wv*8+7
        const int o   = (wv * 2 + j) * 1024 + lane * 16;
        const int row = o >> 8;
        const int c   = (o ^ ((row & 7) << 4)) & 255;
        gsB[j] = tgt_masks + (((long)(b * MQ + min(row, MQ - 1))) << 16)
               + chunk * KC + (c >> 2);
    }
    const int dA = wv * 4096;          // wave-uniform LDS dest bases
    const int dB = ABYTES + wv * 2048;

    // ---- swizzled ds_read base offsets (k-slice 0; +128 for slice 1) ----
    const int ar    = n0 + r16;                               // A row 0..111
    const int aoff0 = ar * 256 + ((kg * 32) ^ ((ar & 7) << 4));
    int boff0[4];
    #pragma unroll
    for (int mt = 0; mt < 4; ++mt) {
        const int rb = min(mt * 16 + r16, 55);  // rows 51..55 junk (unread cols)
        boff0[mt] = ABYTES + rb * 256 + ((kg * 32) ^ ((rb & 7) << 4));
    }

    f32x4 acc1[4], acc2[4];
    #pragma unroll
    for (int mt = 0; mt < 4; ++mt) {
        acc1[mt] = (f32x4){0.f, 0.f, 0.f, 0.f};
        acc2[mt] = (f32x4){0.f, 0.f, 0.f, 0.f};
    }
    float rsl = 0.f;

    // issue this thread's 6 async global->LDS loads for step s (no VGPR cost)
    auto stage = [&](int s) {
        char* dst = lds + (s % DEPTH) * SLAB;
        #pragma unroll
        for (int j = 0; j < 4; ++j)
            __builtin_amdgcn_global_load_lds((as1char*)(const char*)(gsA[j] + s * BK),
                                             (as3char*)(dst + dA + j * 1024), 16, 0, 0);
        #pragma unroll
        for (int j = 0; j < 2; ++j)
            __builtin_amdgcn_global_load_lds((as1char*)(const char*)(gsB[j] + s * BK),
                                             (as3char*)(dst + dB + j * 1024), 16, 0, 0);
    };

    // consume one staged step: 2 k-slices of {ds_read, transform, pack, 8 MFMA}
    auto compute = [&](int s) {
        const char* sb = lds + (s % DEPTH) * SLAB;
        #pragma unroll
        for (int ks = 0; ks < 2; ++ks) {
            const int ao = aoff0 + ks * 128;
            const float4 a0 = *(const float4*)(sb + ao);
            const float4 a1 = *(const float4*)(sb + (ao ^ 16));
            float4 bv0[4], bv1[4];
            #pragma unroll
            for (int mt = 0; mt < 4; ++mt) {
                const int bo = boff0[mt] + ks * 128;
                bv0[mt] = *(const float4*)(sb + bo);
                bv1[mt] = *(const float4*)(sb + (bo ^ 16));
            }

            float d0,d1,d2,d3,d4,d5,d6,d7, p0,p1,p2,p3,p4,p5,p6,p7, l;
            xform2(a0.x, d0, p0, l); rsl += l;
            xform2(a0.y, d1, p1, l); rsl += l;
            xform2(a0.z, d2, p2, l); rsl += l;
            xform2(a0.w, d3, p3, l); rsl += l;
            xform2(a1.x, d4, p4, l); rsl += l;
            xform2(a1.y, d5, p5, l); rsl += l;
            xform2(a1.z, d6, p6, l); rsl += l;
            xform2(a1.w, d7, p7, l); rsl += l;
            short8 fd = mk8s(d0,d1,d2,d3,d4,d5,d6,d7);
            const short8 fp = mk8s(p0,p1,p2,p3,p4,p5,p6,p7);

            {   // acc1 rows 100-111 -> colsum(tm) = St (exact; wave 6 only)
                union { short8 s8; unsigned u[4]; } f; f.s8 = fd;
                f.u[0] = onesrow ? ONESBF2 : f.u[0];
                f.u[1] = onesrow ? ONESBF2 : f.u[1];
                f.u[2] = onesrow ? ONESBF2 : f.u[2];
                f.u[3] = onesrow ? ONESBF2 : f.u[3];
                fd = f.s8;
            }

            #pragma unroll
            for (int mt = 0; mt < 4; ++mt) {
                union { short8 s8; unsigned u[4]; } f;
                f.s8 = mk8(bv0[mt], bv1[mt]);
                if (mt == 3) {  // acc2 col 50 -> rowsum(pm) = Sp
                    f.u[0] = c50 ? ONESBF2 : f.u[0];
                    f.u[1] = c50 ? ONESBF2 : f.u[1];
                    f.u[2] = c50 ? ONESBF2 : f.u[2];
                    f.u[3] = c50 ? ONESBF2 : f.u[3];
                }
                acc1[mt] = __builtin_amdgcn_mfma_f32_16x16x32_bf16(fd, f.s8, acc1[mt], 0, 0, 0);
                acc2[mt] = __builtin_amdgcn_mfma_f32_16x16x32_bf16(fp, f.s8, acc2[mt], 0, 0, 0);
            }
        }
    };

    // prologue: 2 slabs in flight (12 insts/thread outstanding)
    stage(0); stage(1);

    for (int s = 0; s < NSTEPS; ++s) {
        // own slab-s insts oldest; leave slab s+1's 6 in flight.
        if (s < NSTEPS - 1) asm volatile("s_waitcnt vmcnt(6)" ::: "memory");
        else                asm volatile("s_waitcnt vmcnt(0)" ::: "memory");
        // all waves: slab s complete; all waves finished compute(s-1).
        asm volatile("s_barrier" ::: "memory");
        // overwrite buf[(s+2)%3] == buf[(s-1)%3]: safe after the barrier.
        if (s + 2 < NSTEPS) stage(s + 2);
        compute(s);
    }

    // ---- store C partials: C/D layout col=lane&15, row=(lane>>4)*4+reg ----
    const long pbase = ((long)(b * NCH + chunk)) * NP * MP;
    const int nr0 = kg * 4;
    #pragma unroll
    for (int mt = 0; mt < 4; ++mt) {
        const int mloc = mt * 16 + r16;
        #pragma unroll
        for (int r = 0; r < 4; ++r) {
            const int ng = n0 + nr0 + r;
            part1[pbase + ng * MP + mloc] = acc1[mt][r];
            part2[pbase + ng * MP + mloc] = acc2[mt][r];
        }
    }

    // ---- rsl row sums: lanes {r,r+16,r+32,r+48} hold row r's k-partials ----
    rsl += __shfl_xor(rsl, 16); rsl += __shfl_xor(rsl, 32);
    if (lane < 16)
        rspart[(long)(b * NCH + chunk) * NP + n0 + lane] = rsl;
}

// Epilogue: one block per (b,n), 1024 threads; 16-way chunk-group reduction.
// St comes from part1 row 100 (ones-row trick); Sp from part2 col 50
// (ones-col trick); rspart carries only rsl.
__global__ __launch_bounds__(1024)
void matcher_epilogue(const float* __restrict__ pred_logits, // [4][100][2]
                      const float* __restrict__ pred_style,  // [4][100][4]
                      const int*   __restrict__ styles,      // [4][50]
                      const float* __restrict__ part1,
                      const float* __restrict__ part2,
                      const float* __restrict__ rspart,
                      float* __restrict__ out, int nch)
{
    __shared__ float red1[16][64], red2[16][64], redt[16][64];
    __shared__ float slw[16];

    const int blk = blockIdx.x;          // 0..399
    const int b = blk / NQ, n = blk % NQ;
    const int t = threadIdx.x;
    const int m = t & 63, cg = t >> 6;   // cg in 0..15

    float S1 = 0.f, S2 = 0.f, St = 0.f;
    for (int c = cg; c < nch; c += 16) {
        const long cb = (long)(b * nch + c) * NP;
        S1 += part1[(cb + n) * MP + m];
        S2 += part2[(cb + n) * MP + m];
        St += part1[(cb + 100) * MP + m];   // ones-row: colsum(tm), exact
    }
    red1[cg][m] = S1; red2[cg][m] = S2; redt[cg][m] = St;

    // Sl across chunks: threads 0..nch-1 load, per-wave shuffle reduce
    float sl = 0.f;
    if (t < nch)
        sl = rspart[(long)(b * nch + t) * NP + n];
    #pragma unroll
    for (int off = 32; off; off >>= 1) sl += __shfl_down(sl, off);
    if ((t & 63) == 0) slw[t >> 6] = sl;
    __syncthreads();

    if (t < MQ) {
        float Sl = 0.f, Sp = 0.f, s1 = 0.f, s2 = 0.f, st = 0.f;
        #pragma unroll
        for (int w = 0; w < 16; w++) {
            Sl += slw[w];
            Sp += red2[w][50];              // ones-col: rowsum(pm)
            s1 += red1[w][t]; s2 += red2[w][t]; st += redt[w][t];
        }

        // classification: -softmax(logits)[1]
        const float l0 = pred_logits[(b * NQ + n) * 2 + 0];
        const float l1 = pred_logits[(b * NQ + n) * 2 + 1];
        const float p1 = 1.0f / (1.0f + __expf(l0 - l1));

        // style: -softmax(style)[sid]
        const float* stp = &pred_style[(b * NQ + n) * 4];
        const float v0 = stp[0], v1 = stp[1], v2 = stp[2], v3 = stp[3];
        const float mx = fmaxf(fmaxf(v0, v1), fmaxf(v2, v3));
        const float e0 = __expf(v0 - mx), e1 = __expf(v1 - mx),
                    e2 = __expf(v2 - mx), e3 = __expf(v3 - mx);
        const float esum = e0 + e1 + e2 + e3;
        int sid = styles[b * MQ + t];
        sid = min(max(sid, 0), 3);
        const float ps = (sid == 0 ? e0 : sid == 1 ? e1 : sid == 2 ? e2 : e3) / esum;

        const float cost_mask = -(s1 + Sl) * (1.0f / (float)HWSZ);
        const float dice = 1.0f - (2.0f * s2 + 1.0f) / (Sp + st + 1.0f);

        float c = 2.0f * (-p1) + 5.0f * cost_mask + 5.0f * dice + 1.0f * (-ps);
        if (isnan(c)) c = 10000.0f;
        else if (isinf(c)) c = (c > 0.f) ? 10000.0f : -10000.0f;
        out[(b * NQ + n) * MQ + t] = c;
    }
}

extern "C" void kernel_launch(void* const* d_in, const int* in_sizes, int n_in,
                              void* d_out, int out_size, void* d_ws, size_t ws_size,
                              hipStream_t stream) {
    const float* pred_logits = (const float*)d_in[0];
    const float* pred_masks  = (const float*)d_in[1];
    const float* pred_style  = (const float*)d_in[2];
    const float* tgt_masks   = (const float*)d_in[3];
    const int*   styles      = (const int*)d_in[4];
    float* out = (float*)d_out;

    // ws layout: part1/part2 [4][128][112][64], rspart [4][128][112] (29.6 MB)
    float* part1  = (float*)d_ws;
    float* part2  = part1 + (size_t)BQ * NCH * NP * MP;
    float* rspart = part2 + (size_t)BQ * NCH * NP * MP;

    dim3 grid(NCH, BQ);    // 512 blocks x 448 thr; 126KB LDS -> 1 block/CU
    matcher_main<<<grid, 448, DEPTH * SLAB, stream>>>(
        pred_masks, tgt_masks, part1, part2, rspart);

    matcher_epilogue<<<BQ * NQ, 1024, 0, stream>>>(
        pred_logits, pred_style, styles, part1, part2, rspart, out, NCH);
}